// Round 4
// baseline (272.945 us; speedup 1.0000x reference)
//
#include <hip/hip_runtime.h>
#include <math.h>

#define BB 32
#define TT 2048
#define DD 1024
#define NH 16
#define HDIM 64
#define EPS 1e-5f

// ---------------- reduction helpers ----------------
__device__ __forceinline__ float wredSum(float v){
  v += __shfl_down(v, 32, 64);
  v += __shfl_down(v, 16, 64);
  v += __shfl_down(v, 8, 64);
  v += __shfl_down(v, 4, 64);
  v += __shfl_down(v, 2, 64);
  v += __shfl_down(v, 1, 64);
  return v;
}
__device__ float bredSum(float v, float* red){
  int lane = threadIdx.x & 63, w = threadIdx.x >> 6, nw = blockDim.x >> 6;
  v = wredSum(v);
  __syncthreads();
  if (lane == 0) red[w] = v;
  __syncthreads();
  if (w == 0){
    float x = (lane < nw) ? red[lane] : 0.f;
    x = wredSum(x);
    if (lane == 0) red[0] = x;
  }
  __syncthreads();
  return red[0];
}

// ---------------- K0a: q = LN(h_t)*tau ----------------
__global__ __launch_bounds__(256) void k_qln(const float* __restrict__ h_t,
   const float* __restrict__ g, const float* __restrict__ bb,
   const float* __restrict__ log_tau, float* __restrict__ q)
{
  int b = blockIdx.x, tid = threadIdx.x;
  __shared__ float red[64];
  float4 x = ((const float4*)(h_t + (size_t)b*DD))[tid];
  float s = x.x + x.y + x.z + x.w;
  s = bredSum(s, red);
  float mu = s * (1.f/DD);
  float d0=x.x-mu, d1=x.y-mu, d2=x.z-mu, d3=x.w-mu;
  float s2 = d0*d0 + d1*d1 + d2*d2 + d3*d3;
  s2 = bredSum(s2, red);
  float rs = rsqrtf(s2*(1.f/DD) + EPS);
  float tau = fminf(fmaxf(expf(log_tau[0]), 0.25f), 4.0f);
  float4 gv = ((const float4*)g)[tid], bv = ((const float4*)bb)[tid];
  float4 o;
  o.x = (d0*rs*gv.x + bv.x)*tau;
  o.y = (d1*rs*gv.y + bv.y)*tau;
  o.z = (d2*rs*gv.z + bv.z)*tau;
  o.w = (d3*rs*gv.w + bv.w)*tau;
  ((float4*)(q + (size_t)b*DD))[tid] = o;
}

// ------------- small GEMM (32x1024 @ 1024x1024^T), d-split partials -------------
__global__ __launch_bounds__(256) void k_gemmsplit(const float* __restrict__ A,
    const float* __restrict__ W, float* __restrict__ p2)
{
  int ec = blockIdx.x, ds = blockIdx.y;
  int tid = threadIdx.x;
  __shared__ float Wl[64][132];
  __shared__ float Al[32][132];
  int d0 = ds*128, e0 = ec*64;
#pragma unroll
  for (int p=0;p<8;p++){
    int fi = p*256 + tid, r = fi >> 5, q4 = fi & 31;
    float4 v = *(const float4*)(W + (size_t)(e0+r)*DD + d0 + q4*4);
    *(float4*)&Wl[r][q4*4] = v;
  }
#pragma unroll
  for (int p=0;p<4;p++){
    int fi = p*256 + tid, r = fi >> 5, q4 = fi & 31;
    float4 v = *(const float4*)(A + (size_t)r*DD + d0 + q4*4);
    *(float4*)&Al[r][q4*4] = v;
  }
  __syncthreads();
  int eL = tid & 63, bg = tid >> 6;
  float acc[8];
#pragma unroll
  for (int i=0;i<8;i++) acc[i]=0.f;
  for (int d4=0; d4<32; d4++){
    float4 w = *(float4*)&Wl[eL][d4*4];
#pragma unroll
    for (int i=0;i<8;i++){
      float4 a = *(float4*)&Al[bg*8+i][d4*4];
      acc[i] = fmaf(w.x, a.x, acc[i]);
      acc[i] = fmaf(w.y, a.y, acc[i]);
      acc[i] = fmaf(w.z, a.z, acc[i]);
      acc[i] = fmaf(w.w, a.w, acc[i]);
    }
  }
#pragma unroll
  for (int i=0;i<8;i++)
    p2[((size_t)ds*BB + (bg*8+i))*DD + e0 + eL] = acc[i];
}

// ------------- K0c: qh-reduce (fused) + s = Wk_h^T qh_h ; gs_t, gsum, cst -------------
__global__ __launch_bounds__(256) void k_prep_s(const float* __restrict__ p2,
    const float* __restrict__ Wfull, const float* __restrict__ bfull,
    const float* __restrict__ g_kv, const float* __restrict__ b_kv,
    float* __restrict__ gs_t, float* __restrict__ gsum, float* __restrict__ cst)
{
  int h = blockIdx.x, b = blockIdx.y;
  int tid = threadIdx.x;
  __shared__ float qhl[64];
  __shared__ float red[64];
  if (tid < 64){
    float s = bfull[h*HDIM + tid];   // bq
#pragma unroll
    for (int k=0;k<8;k++)
      s += p2[((size_t)k*BB + b)*DD + h*HDIM + tid];
    qhl[tid] = s;
  }
  __syncthreads();
  float lgs = 0.f, lbs = 0.f;
  const float* Wk = Wfull + (size_t)DD*DD;
#pragma unroll 1
  for (int d = tid; d < DD; d += 256){
    float s = 0.f;
#pragma unroll 8
    for (int j=0;j<64;j++)
      s = fmaf(Wk[(size_t)(h*HDIM+j)*DD + d], qhl[j], s);
    float gsv = s * g_kv[d];
    gs_t[((size_t)b*DD + d)*NH + h] = gsv;
    lgs += gsv;
    lbs = fmaf(s, b_kv[d], lbs);
  }
  float lc = 0.f;
  if (tid < 64) lc = qhl[tid] * bfull[DD + h*HDIM + tid];  // qh . bk
  float tg = bredSum(lgs, red);
  float tb = bredSum(lbs + lc, red);
  if (tid == 0){ gsum[b*NH+h] = tg; cst[b*NH+h] = tb; }
}

// ------------- K1: d-split partial scores, 2 rows/thread -------------
// block: 128 t-rows x 256 d (one of 4 d-splits); 256 threads = (row, hq),
// thread handles rows row and row+64 -> g-broadcast reads amortized 2x.
#define SR 128
#define SDC 64
#define DSPLIT 4
#define DPS (DD/DSPLIT)
#define NCH (DPS/SDC)
__global__ __launch_bounds__(256) void k_scores(
    const float* __restrict__ X, const int* __restrict__ valid,
    const float* __restrict__ gs_t,
    float4* __restrict__ pacc, float2* __restrict__ pstat)
{
  int bx = blockIdx.x, b = blockIdx.y;
  int tc = bx & (TT/SR - 1), ds = bx >> 4;   // TT/SR == 16
  int t0 = tc * SR;
  if (t0 >= valid[b]) return;
  int tid = threadIdx.x;
  int row = tid & 63, hq = tid >> 6, rx = row & 15;
  __shared__ float4 xt[2][SR*16];    // 32KB x2, swizzle u = cg ^ (r&15)
  __shared__ float4 gt[2][SDC*4];    // 4KB x2: [d][h-quad]
  const float* xb = X + ((size_t)b*TT + t0)*DD + ds*DPS;
  const float4* gsrc = (const float4*)(gs_t + ((size_t)b*DD + ds*DPS)*NH);
  int r0 = tid >> 4, cg0 = tid & 15;
  float4 ld[8]; float4 gld;
  float aA0=0.f,aA1=0.f,aA2=0.f,aA3=0.f, aB0=0.f,aB1=0.f,aB2=0.f,aB3=0.f;
  float ssA=0.f, sqA=0.f, ssB=0.f, sqB=0.f;

#define LOADC(c) { const float* pb = xb + (c)*SDC; \
    ld[0] = *(const float4*)(pb + (size_t)(r0+  0)*DD + cg0*4); \
    ld[1] = *(const float4*)(pb + (size_t)(r0+ 16)*DD + cg0*4); \
    ld[2] = *(const float4*)(pb + (size_t)(r0+ 32)*DD + cg0*4); \
    ld[3] = *(const float4*)(pb + (size_t)(r0+ 48)*DD + cg0*4); \
    ld[4] = *(const float4*)(pb + (size_t)(r0+ 64)*DD + cg0*4); \
    ld[5] = *(const float4*)(pb + (size_t)(r0+ 80)*DD + cg0*4); \
    ld[6] = *(const float4*)(pb + (size_t)(r0+ 96)*DD + cg0*4); \
    ld[7] = *(const float4*)(pb + (size_t)(r0+112)*DD + cg0*4); \
    gld = gsrc[(c)*256 + tid]; }
#define STOREC(c) { float4* tb = xt[(c)&1]; int u = cg0 ^ r0; \
    tb[(r0+  0)*16 + u] = ld[0]; \
    tb[(r0+ 16)*16 + u] = ld[1]; \
    tb[(r0+ 32)*16 + u] = ld[2]; \
    tb[(r0+ 48)*16 + u] = ld[3]; \
    tb[(r0+ 64)*16 + u] = ld[4]; \
    tb[(r0+ 80)*16 + u] = ld[5]; \
    tb[(r0+ 96)*16 + u] = ld[6]; \
    tb[(r0+112)*16 + u] = ld[7]; \
    gt[(c)&1][tid] = gld; }

  LOADC(0);
  STOREC(0);
  for (int c = 0; c < NCH; ++c){
    if (c+1 < NCH) LOADC(c+1);
    __syncthreads();
    {
      const float4* tbA = xt[c&1] + row*16;
      const float4* tbB = xt[c&1] + (row+64)*16;
      const float4* gb = gt[c&1];
#pragma unroll
      for (int d4=0; d4<16; d4++){
        float4 xA = tbA[d4 ^ rx];
        float4 xB = tbB[d4 ^ rx];
        float4 g0 = gb[d4*16 + hq];
        float4 g1 = gb[d4*16 + 4 + hq];
        float4 g2 = gb[d4*16 + 8 + hq];
        float4 g3 = gb[d4*16 + 12 + hq];
        ssA += xA.x + xA.y + xA.z + xA.w;
        sqA = fmaf(xA.x,xA.x,sqA); sqA = fmaf(xA.y,xA.y,sqA);
        sqA = fmaf(xA.z,xA.z,sqA); sqA = fmaf(xA.w,xA.w,sqA);
        aA0 = fmaf(xA.x,g0.x,aA0); aA1 = fmaf(xA.x,g0.y,aA1);
        aA2 = fmaf(xA.x,g0.z,aA2); aA3 = fmaf(xA.x,g0.w,aA3);
        aA0 = fmaf(xA.y,g1.x,aA0); aA1 = fmaf(xA.y,g1.y,aA1);
        aA2 = fmaf(xA.y,g1.z,aA2); aA3 = fmaf(xA.y,g1.w,aA3);
        aA0 = fmaf(xA.z,g2.x,aA0); aA1 = fmaf(xA.z,g2.y,aA1);
        aA2 = fmaf(xA.z,g2.z,aA2); aA3 = fmaf(xA.z,g2.w,aA3);
        aA0 = fmaf(xA.w,g3.x,aA0); aA1 = fmaf(xA.w,g3.y,aA1);
        aA2 = fmaf(xA.w,g3.z,aA2); aA3 = fmaf(xA.w,g3.w,aA3);
        ssB += xB.x + xB.y + xB.z + xB.w;
        sqB = fmaf(xB.x,xB.x,sqB); sqB = fmaf(xB.y,xB.y,sqB);
        sqB = fmaf(xB.z,xB.z,sqB); sqB = fmaf(xB.w,xB.w,sqB);
        aB0 = fmaf(xB.x,g0.x,aB0); aB1 = fmaf(xB.x,g0.y,aB1);
        aB2 = fmaf(xB.x,g0.z,aB2); aB3 = fmaf(xB.x,g0.w,aB3);
        aB0 = fmaf(xB.y,g1.x,aB0); aB1 = fmaf(xB.y,g1.y,aB1);
        aB2 = fmaf(xB.y,g1.z,aB2); aB3 = fmaf(xB.y,g1.w,aB3);
        aB0 = fmaf(xB.z,g2.x,aB0); aB1 = fmaf(xB.z,g2.y,aB1);
        aB2 = fmaf(xB.z,g2.z,aB2); aB3 = fmaf(xB.z,g2.w,aB3);
        aB0 = fmaf(xB.w,g3.x,aB0); aB1 = fmaf(xB.w,g3.y,aB1);
        aB2 = fmaf(xB.w,g3.z,aB2); aB3 = fmaf(xB.w,g3.w,aB3);
      }
    }
    if (c+1 < NCH){
      __syncthreads();
      STOREC(c+1);
    }
  }
#undef LOADC
#undef STOREC
  int t = t0 + row;
  size_t pbase = ((size_t)(ds*BB + b)*4 + hq)*TT;
  pacc[pbase + t]      = make_float4(aA0,aA1,aA2,aA3);
  pacc[pbase + t + 64] = make_float4(aB0,aB1,aB2,aB3);
  if (hq == 0){
    pstat[(size_t)(ds*BB + b)*TT + t]      = make_float2(ssA, sqA);
    pstat[(size_t)(ds*BB + b)*TT + t + 64] = make_float2(ssB, sqB);
  }
}

// ------------- K2: fused d-split reduce + online masked softmax + alpha/beta -------------
// grid (4 head-quads, B), 256 threads; thread strides t, handles 4 heads (float4).
__global__ __launch_bounds__(256) void k_softmax2(
    const float4* __restrict__ pacc, const float2* __restrict__ pstat,
    const int* __restrict__ valid, const float* __restrict__ gsum,
    const float* __restrict__ cst, float* __restrict__ alpha_t,
    float* __restrict__ beta)
{
  int hq = blockIdx.x, b = blockIdx.y;
  int n = valid[b];
  int tid = threadIdx.x, lane = tid & 63, w = tid >> 6;
  float4 gq = *(const float4*)(gsum + b*NH + hq*4);
  float4 cq = *(const float4*)(cst  + b*NH + hq*4);
  float m[4], S[4], Bv[4];
#pragma unroll
  for (int j=0;j<4;j++){ m[j] = -3.0e38f; S[j]=0.f; Bv[j]=0.f; }
  for (int t = tid; t < n; t += 256){
    float4 s = make_float4(0.f,0.f,0.f,0.f);
    float ss=0.f, sq=0.f;
#pragma unroll
    for (int k=0;k<DSPLIT;k++){
      float4 v = pacc[((size_t)(k*BB+b)*4+hq)*TT + t];
      s.x+=v.x; s.y+=v.y; s.z+=v.z; s.w+=v.w;
      float2 st = pstat[(size_t)(k*BB+b)*TT + t];
      ss += st.x; sq += st.y;
    }
    float mu = ss*(1.f/DD);
    float rs = rsqrtf(sq*(1.f/DD) - mu*mu + EPS);
    float rm = rs*mu;
    float sc[4];
    sc[0] = (rs*(s.x - mu*gq.x) + cq.x)*0.125f;
    sc[1] = (rs*(s.y - mu*gq.y) + cq.y)*0.125f;
    sc[2] = (rs*(s.z - mu*gq.z) + cq.z)*0.125f;
    sc[3] = (rs*(s.w - mu*gq.w) + cq.w)*0.125f;
#pragma unroll
    for (int j=0;j<4;j++){
      float M = fmaxf(m[j], sc[j]);
      float f = expf(m[j]-M);
      float e = expf(sc[j]-M);
      S[j]  = S[j]*f + e;
      Bv[j] = Bv[j]*f + e*rm;
      m[j] = M;
    }
  }
  // wave-level merge
#pragma unroll
  for (int off = 32; off >= 1; off >>= 1){
#pragma unroll
    for (int j=0;j<4;j++){
      float om = __shfl_xor(m[j], off, 64);
      float oS = __shfl_xor(S[j], off, 64);
      float oB = __shfl_xor(Bv[j], off, 64);
      float M = fmaxf(m[j], om);
      float f1 = expf(m[j]-M), f2 = expf(om-M);
      S[j]  = S[j]*f1 + oS*f2;
      Bv[j] = Bv[j]*f1 + oB*f2;
      m[j] = M;
    }
  }
  __shared__ float sm[4][12];
  if (lane == 0){
#pragma unroll
    for (int j=0;j<4;j++){ sm[w][j]=m[j]; sm[w][4+j]=S[j]; sm[w][8+j]=Bv[j]; }
  }
  __syncthreads();
#pragma unroll
  for (int j=0;j<4;j++){ m[j]=sm[0][j]; S[j]=sm[0][4+j]; Bv[j]=sm[0][8+j]; }
#pragma unroll
  for (int w2=1; w2<4; w2++){
#pragma unroll
    for (int j=0;j<4;j++){
      float om = sm[w2][j], oS = sm[w2][4+j], oB = sm[w2][8+j];
      float M = fmaxf(m[j], om);
      float f1 = expf(m[j]-M), f2 = expf(om-M);
      S[j]  = S[j]*f1 + oS*f2;
      Bv[j] = Bv[j]*f1 + oB*f2;
      m[j] = M;
    }
  }
  float inv[4];
#pragma unroll
  for (int j=0;j<4;j++) inv[j] = 1.f/S[j];
  if (tid == 0){
#pragma unroll
    for (int j=0;j<4;j++) beta[b*NH + hq*4 + j] = Bv[j]*inv[j];
  }
  // pass 2: recompute scores, write alpha (float4 per t, 4 heads)
  for (int t = tid; t < n; t += 256){
    float4 s = make_float4(0.f,0.f,0.f,0.f);
    float ss=0.f, sq=0.f;
#pragma unroll
    for (int k=0;k<DSPLIT;k++){
      float4 v = pacc[((size_t)(k*BB+b)*4+hq)*TT + t];
      s.x+=v.x; s.y+=v.y; s.z+=v.z; s.w+=v.w;
      float2 st = pstat[(size_t)(k*BB+b)*TT + t];
      ss += st.x; sq += st.y;
    }
    float mu = ss*(1.f/DD);
    float rs = rsqrtf(sq*(1.f/DD) - mu*mu + EPS);
    float4 av;
    av.x = expf((rs*(s.x - mu*gq.x) + cq.x)*0.125f - m[0]) * rs * inv[0];
    av.y = expf((rs*(s.y - mu*gq.y) + cq.y)*0.125f - m[1]) * rs * inv[1];
    av.z = expf((rs*(s.z - mu*gq.z) + cq.z)*0.125f - m[2]) * rs * inv[2];
    av.w = expf((rs*(s.w - mu*gq.w) + cq.w)*0.125f - m[3]) * rs * inv[3];
    *(float4*)(alpha_t + ((size_t)b*TT + t)*NH + hq*4) = av;
  }
}

// ------------- K3: partial u accumulation (alpha staged in LDS) -------------
__global__ __launch_bounds__(512) void k_accum(
    const float* __restrict__ X, const float* __restrict__ alpha_t,
    const int* __restrict__ valid, float* __restrict__ part, int ct)
{
  int c = blockIdx.x, b = blockIdx.y;
  int tid = threadIdx.x;
  int t0 = c*ct;
  int tend = min(valid[b], t0 + ct);
  float ax[16], ay[16];
#pragma unroll
  for (int h=0;h<16;h++){ ax[h]=0.f; ay[h]=0.f; }
  __shared__ float4 at[2][256];
  if (t0 < tend){
    const float2* xb = (const float2*)(X + (size_t)b*TT*DD);
    const float4* ab = (const float4*)(alpha_t + (size_t)b*TT*NH);
    int nsub = (tend - t0 + 63) >> 6;
    float4 nxt = make_float4(0.f,0.f,0.f,0.f);
    if (tid < 256) at[0][tid] = ab[(size_t)t0*4 + tid];
    for (int s=0; s<nsub; s++){
      if (s+1 < nsub && tid < 256) nxt = ab[(size_t)(t0+(s+1)*64)*4 + tid];
      __syncthreads();
      int ts = t0 + s*64;
      int te = min(tend - ts, 64);
      const float4* av = at[s&1];
      float2 xv = xb[(size_t)ts*(DD/2) + tid];
      for (int tl=0; tl<te; tl++){
        float2 xc = xv;
        if (tl+1 < te) xv = xb[(size_t)(ts+tl+1)*(DD/2) + tid];
        float4 q0 = av[tl*4+0], q1 = av[tl*4+1], q2 = av[tl*4+2], q3 = av[tl*4+3];
        float a[16] = {q0.x,q0.y,q0.z,q0.w, q1.x,q1.y,q1.z,q1.w,
                       q2.x,q2.y,q2.z,q2.w, q3.x,q3.y,q3.z,q3.w};
#pragma unroll
        for (int h=0;h<16;h++){
          ax[h] = fmaf(a[h], xc.x, ax[h]);
          ay[h] = fmaf(a[h], xc.y, ay[h]);
        }
      }
      if (s+1 < nsub){
        __syncthreads();
        if (tid < 256) at[(s+1)&1][tid] = nxt;
      }
    }
  }
  float* pp = part + (((size_t)c*BB + b)*NH)*DD;
#pragma unroll
  for (int h=0;h<16;h++)
    *(float2*)(pp + (size_t)h*DD + tid*2) = make_float2(ax[h], ay[h]);
}

// ------------- K4: fused u-finalize + ctx = Wv_h @ u + bv -------------
__global__ __launch_bounds__(256) void k_uctx(const float* __restrict__ part,
   const float* __restrict__ beta, const float* __restrict__ g_kv,
   const float* __restrict__ b_kv, const float* __restrict__ Wfull,
   const float* __restrict__ bfull, float* __restrict__ ctx, int nc)
{
  int h = blockIdx.x, b = blockIdx.y;
  int tid = threadIdx.x;
  __shared__ float ul[DD];
  __shared__ float Wl[64][65];
  __shared__ float red2[4][64];
  {
    int d = tid*4;
    float4 s = make_float4(0.f,0.f,0.f,0.f);
    for (int c=0;c<nc;c++){
      float4 v = *(const float4*)(part + (((size_t)c*BB + b)*NH + h)*DD + d);
      s.x+=v.x; s.y+=v.y; s.z+=v.z; s.w+=v.w;
    }
    float be = beta[b*NH+h];
    float4 g = *(const float4*)(g_kv + d);
    float4 bv = *(const float4*)(b_kv + d);
    float4 r;
    r.x = fmaf(g.x, s.x-be, bv.x);
    r.y = fmaf(g.y, s.y-be, bv.y);
    r.z = fmaf(g.z, s.z-be, bv.z);
    r.w = fmaf(g.w, s.w-be, bv.w);
    ((float4*)ul)[tid] = r;
  }
  __syncthreads();
  int j = tid & 63, quart = tid >> 6;
  float acc = 0.f;
  const float* Wv = Wfull + (size_t)2*DD*DD;
  for (int dc=0; dc<DD; dc+=64){
#pragma unroll
    for (int p=0;p<4;p++){
      int fi = p*256 + tid, r = fi >> 4, q4 = fi & 15;
      float4 v = *(const float4*)(Wv + (size_t)(h*HDIM + r)*DD + dc + q4*4);
      Wl[r][q4*4+0]=v.x; Wl[r][q4*4+1]=v.y; Wl[r][q4*4+2]=v.z; Wl[r][q4*4+3]=v.w;
    }
    __syncthreads();
#pragma unroll
    for (int i=0;i<16;i++)
      acc = fmaf(Wl[j][quart*16+i], ul[dc + quart*16 + i], acc);
    __syncthreads();
  }
  red2[quart][j] = acc;
  __syncthreads();
  if (quart == 0){
    float v = red2[0][j] + red2[1][j] + red2[2][j] + red2[3][j];
    ctx[(size_t)b*DD + h*HDIM + j] = v + bfull[2*DD + h*HDIM + j];
  }
}

// ------------- K5: fused out-proj reduce + out = LN(o + h_t) -------------
__global__ __launch_bounds__(256) void k_outln(const float* __restrict__ p2,
   const float* __restrict__ obias, const float* __restrict__ h_t,
   const float* __restrict__ g, const float* __restrict__ bb,
   float* __restrict__ out)
{
  int b = blockIdx.x, tid = threadIdx.x;
  __shared__ float red[64];
  int e = tid*4;
  float4 a = *(const float4*)(obias + e);
#pragma unroll
  for (int k=0;k<8;k++){
    float4 v = *(const float4*)(p2 + ((size_t)k*BB + b)*DD + e);
    a.x+=v.x; a.y+=v.y; a.z+=v.z; a.w+=v.w;
  }
  float4 r = ((const float4*)(h_t + (size_t)b*DD))[tid];
  a.x+=r.x; a.y+=r.y; a.z+=r.z; a.w+=r.w;
  float s = a.x + a.y + a.z + a.w;
  s = bredSum(s, red);
  float mu = s * (1.f/DD);
  float d0=a.x-mu, d1=a.y-mu, d2=a.z-mu, d3=a.w-mu;
  float s2 = d0*d0 + d1*d1 + d2*d2 + d3*d3;
  s2 = bredSum(s2, red);
  float rs = rsqrtf(s2*(1.f/DD) + EPS);
  float4 gv = ((const float4*)g)[tid], bv = ((const float4*)bb)[tid];
  float4 ov;
  ov.x = fmaf(d0*rs, gv.x, bv.x);
  ov.y = fmaf(d1*rs, gv.y, bv.y);
  ov.z = fmaf(d2*rs, gv.z, bv.z);
  ov.w = fmaf(d3*rs, gv.w, bv.w);
  ((float4*)(out + (size_t)b*DD))[tid] = ov;
}

extern "C" void kernel_launch(void* const* d_in, const int* in_sizes, int n_in,
                              void* d_out, int out_size, void* d_ws, size_t ws_size,
                              hipStream_t stream) {
  const float* h_t     = (const float*)d_in[0];
  const float* H_p     = (const float*)d_in[1];
  const int*   valid   = (const int*)  d_in[2];
  const float* ln_q_g  = (const float*)d_in[3];
  const float* ln_q_b  = (const float*)d_in[4];
  const float* ln_kv_g = (const float*)d_in[5];
  const float* ln_kv_b = (const float*)d_in[6];
  const float* ln_out_g= (const float*)d_in[7];
  const float* ln_out_b= (const float*)d_in[8];
  const float* log_tau = (const float*)d_in[9];
  const float* in_w    = (const float*)d_in[10];
  const float* in_b    = (const float*)d_in[11];
  const float* out_w   = (const float*)d_in[12];
  const float* out_b   = (const float*)d_in[13];
  float* out = (float*)d_out;

  float* ws     = (float*)d_ws;
  float* q      = ws;
  float* gs_t   = q      + BB*DD;
  float* gsum   = gs_t   + (size_t)BB*DD*NH;
  float* cst    = gsum   + BB*NH;
  float* alpha  = cst    + BB*NH;
  float* beta   = alpha  + (size_t)BB*TT*NH;
  float* ctx    = beta   + BB*NH;
  float* part   = ctx    + BB*DD;
  // "part" region is time-shared: in-proj gemm partials (consumed by k_prep_s),
  // then pacc/pstat (consumed by k_softmax2), then accum partials (k_accum ->
  // k_uctx), then out-proj gemm partials (consumed by k_outln).
  float4* pacc  = (float4*)part;                     // 4,194,304 floats
  float2* pstat = (float2*)(part + (size_t)4194304); //   524,288 floats

  size_t base_floats = (size_t)(part - ws);
  const size_t pacc_region = 4194304 + 524288;
  int nc = 16;
  size_t accum_region = (size_t)nc*BB*NH*DD;
  size_t region = accum_region > pacc_region ? accum_region : pacc_region;
  if ((base_floats + region) * sizeof(float) > ws_size){
    nc = 8;
  }
  int ct = TT / nc;

  k_qln<<<BB, 256, 0, stream>>>(h_t, ln_q_g, ln_q_b, log_tau, q);
  k_gemmsplit<<<dim3(16,8), 256, 0, stream>>>(q, in_w, part);
  k_prep_s<<<dim3(NH,BB), 256, 0, stream>>>(part, in_w, in_b, ln_kv_g, ln_kv_b, gs_t, gsum, cst);
  k_scores<<<dim3((TT/SR)*DSPLIT,BB), 256, 0, stream>>>(H_p, valid, gs_t, pacc, pstat);
  k_softmax2<<<dim3(4,BB), 256, 0, stream>>>(pacc, pstat, valid, gsum, cst, alpha, beta);
  k_accum<<<dim3(nc,BB), 512, 0, stream>>>(H_p, alpha, valid, part, ct);
  k_uctx<<<dim3(NH,BB), 256, 0, stream>>>(part, beta, ln_kv_g, ln_kv_b, in_w, in_b, ctx, nc);
  k_gemmsplit<<<dim3(16,8), 256, 0, stream>>>(ctx, out_w, part);
  k_outln<<<BB, 256, 0, stream>>>(part, out_b, h_t, ln_out_g, ln_out_b, out);
}

// Round 5
// 154.834 us; speedup vs baseline: 1.7628x; 1.7628x over previous
//
#include <hip/hip_runtime.h>
#include <math.h>

#define BB 32
#define TT 2048
#define DD 1024
#define NH 16
#define HDIM 64
#define EPS 1e-5f

// ---------------- reduction helpers ----------------
__device__ __forceinline__ float wredSum(float v){
  v += __shfl_down(v, 32, 64);
  v += __shfl_down(v, 16, 64);
  v += __shfl_down(v, 8, 64);
  v += __shfl_down(v, 4, 64);
  v += __shfl_down(v, 2, 64);
  v += __shfl_down(v, 1, 64);
  return v;
}
__device__ float bredSum(float v, float* red){
  int lane = threadIdx.x & 63, w = threadIdx.x >> 6, nw = blockDim.x >> 6;
  v = wredSum(v);
  __syncthreads();
  if (lane == 0) red[w] = v;
  __syncthreads();
  if (w == 0){
    float x = (lane < nw) ? red[lane] : 0.f;
    x = wredSum(x);
    if (lane == 0) red[0] = x;
  }
  __syncthreads();
  return red[0];
}

// ---------------- K0a: q = LN(h_t)*tau ----------------
__global__ __launch_bounds__(256) void k_qln(const float* __restrict__ h_t,
   const float* __restrict__ g, const float* __restrict__ bb,
   const float* __restrict__ log_tau, float* __restrict__ q)
{
  int b = blockIdx.x, tid = threadIdx.x;
  __shared__ float red[64];
  float4 x = ((const float4*)(h_t + (size_t)b*DD))[tid];
  float s = x.x + x.y + x.z + x.w;
  s = bredSum(s, red);
  float mu = s * (1.f/DD);
  float d0=x.x-mu, d1=x.y-mu, d2=x.z-mu, d3=x.w-mu;
  float s2 = d0*d0 + d1*d1 + d2*d2 + d3*d3;
  s2 = bredSum(s2, red);
  float rs = rsqrtf(s2*(1.f/DD) + EPS);
  float tau = fminf(fmaxf(expf(log_tau[0]), 0.25f), 4.0f);
  float4 gv = ((const float4*)g)[tid], bv = ((const float4*)bb)[tid];
  float4 o;
  o.x = (d0*rs*gv.x + bv.x)*tau;
  o.y = (d1*rs*gv.y + bv.y)*tau;
  o.z = (d2*rs*gv.z + bv.z)*tau;
  o.w = (d3*rs*gv.w + bv.w)*tau;
  ((float4*)(q + (size_t)b*DD))[tid] = o;
}

// ------------- small GEMM (32x1024 @ 1024x1024^T), d-split partials -------------
__global__ __launch_bounds__(256) void k_gemmsplit(const float* __restrict__ A,
    const float* __restrict__ W, float* __restrict__ p2)
{
  int ec = blockIdx.x, ds = blockIdx.y;
  int tid = threadIdx.x;
  __shared__ float Wl[64][132];
  __shared__ float Al[32][132];
  int d0 = ds*128, e0 = ec*64;
#pragma unroll
  for (int p=0;p<8;p++){
    int fi = p*256 + tid, r = fi >> 5, q4 = fi & 31;
    float4 v = *(const float4*)(W + (size_t)(e0+r)*DD + d0 + q4*4);
    *(float4*)&Wl[r][q4*4] = v;
  }
#pragma unroll
  for (int p=0;p<4;p++){
    int fi = p*256 + tid, r = fi >> 5, q4 = fi & 31;
    float4 v = *(const float4*)(A + (size_t)r*DD + d0 + q4*4);
    *(float4*)&Al[r][q4*4] = v;
  }
  __syncthreads();
  int eL = tid & 63, bg = tid >> 6;
  float acc[8];
#pragma unroll
  for (int i=0;i<8;i++) acc[i]=0.f;
  for (int d4=0; d4<32; d4++){
    float4 w = *(float4*)&Wl[eL][d4*4];
#pragma unroll
    for (int i=0;i<8;i++){
      float4 a = *(float4*)&Al[bg*8+i][d4*4];
      acc[i] = fmaf(w.x, a.x, acc[i]);
      acc[i] = fmaf(w.y, a.y, acc[i]);
      acc[i] = fmaf(w.z, a.z, acc[i]);
      acc[i] = fmaf(w.w, a.w, acc[i]);
    }
  }
#pragma unroll
  for (int i=0;i<8;i++)
    p2[((size_t)ds*BB + (bg*8+i))*DD + e0 + eL] = acc[i];
}

// ------------- K0c: qh-reduce (fused) + s = Wk_h^T qh_h ; gs_t, gsum, cst -------------
__global__ __launch_bounds__(256) void k_prep_s(const float* __restrict__ p2,
    const float* __restrict__ Wfull, const float* __restrict__ bfull,
    const float* __restrict__ g_kv, const float* __restrict__ b_kv,
    float* __restrict__ gs_t, float* __restrict__ gsum, float* __restrict__ cst)
{
  int h = blockIdx.x, b = blockIdx.y;
  int tid = threadIdx.x;
  __shared__ float qhl[64];
  __shared__ float red[64];
  if (tid < 64){
    float s = bfull[h*HDIM + tid];   // bq
#pragma unroll
    for (int k=0;k<8;k++)
      s += p2[((size_t)k*BB + b)*DD + h*HDIM + tid];
    qhl[tid] = s;
  }
  __syncthreads();
  float lgs = 0.f, lbs = 0.f;
  const float* Wk = Wfull + (size_t)DD*DD;
#pragma unroll 1
  for (int d = tid; d < DD; d += 256){
    float s = 0.f;
#pragma unroll 8
    for (int j=0;j<64;j++)
      s = fmaf(Wk[(size_t)(h*HDIM+j)*DD + d], qhl[j], s);
    float gsv = s * g_kv[d];
    gs_t[((size_t)b*DD + d)*NH + h] = gsv;
    lgs += gsv;
    lbs = fmaf(s, b_kv[d], lbs);
  }
  float lc = 0.f;
  if (tid < 64) lc = qhl[tid] * bfull[DD + h*HDIM + tid];  // qh . bk
  float tg = bredSum(lgs, red);
  float tb = bredSum(lbs + lc, red);
  if (tid == 0){ gsum[b*NH+h] = tg; cst[b*NH+h] = tb; }
}

// ------------- K1: d-split partial scores, occupancy-first -------------
// block: 64 t-rows x 512 d (one of 2 d-splits); 256 threads = (row, hq).
// 40KB LDS (4 blocks/CU), VGPR capped 128 (4 waves/SIMD) -> 16 waves/CU.
#define SR 64
#define SDC 64
#define DSPLIT 2
#define DPS (DD/DSPLIT)
#define NCH (DPS/SDC)
__global__ __launch_bounds__(256, 4) void k_scores(
    const float* __restrict__ X, const int* __restrict__ valid,
    const float* __restrict__ gs_t,
    float4* __restrict__ pacc, float2* __restrict__ pstat)
{
  int bx = blockIdx.x, b = blockIdx.y;
  int tc = bx & (TT/SR - 1), ds = bx >> 5;   // TT/SR == 32
  int t0 = tc * SR;
  if (t0 >= valid[b]) return;
  int tid = threadIdx.x;
  int row = tid & 63, hq = tid >> 6, rx = row & 15;
  __shared__ float4 xt[2][SR*16];    // 16KB x2, swizzle u = cg ^ (r&15)
  __shared__ float4 gt[2][SDC*4];    // 4KB x2: [d][h-quad]
  const float* xb = X + ((size_t)b*TT + t0)*DD + ds*DPS;
  const float4* gsrc = (const float4*)(gs_t + ((size_t)b*DD + ds*DPS)*NH);
  int r0 = tid >> 4, cg0 = tid & 15;
  float4 ld0, ld1, ld2, ld3, gld;
  float a0=0.f, a1=0.f, a2=0.f, a3=0.f, ssum=0.f, ssq=0.f;
#define LOADC(c) { const float* pb = xb + (c)*SDC; \
    ld0 = *(const float4*)(pb + (size_t)(r0+ 0)*DD + cg0*4); \
    ld1 = *(const float4*)(pb + (size_t)(r0+16)*DD + cg0*4); \
    ld2 = *(const float4*)(pb + (size_t)(r0+32)*DD + cg0*4); \
    ld3 = *(const float4*)(pb + (size_t)(r0+48)*DD + cg0*4); \
    gld = gsrc[(c)*256 + tid]; }
#define STOREC(c) { float4* tb = xt[(c)&1]; int u = cg0 ^ r0; \
    tb[(r0+ 0)*16 + u] = ld0; \
    tb[(r0+16)*16 + u] = ld1; \
    tb[(r0+32)*16 + u] = ld2; \
    tb[(r0+48)*16 + u] = ld3; \
    gt[(c)&1][tid] = gld; }

  LOADC(0);
  STOREC(0);
  for (int c = 0; c < NCH; ++c){
    if (c+1 < NCH) LOADC(c+1);
    __syncthreads();
    {
      const float4* tb = xt[c&1] + row*16;
      const float4* gb = gt[c&1];
#pragma unroll
      for (int d4=0; d4<16; d4++){
        float4 xv = tb[d4 ^ rx];
        float4 g0 = gb[d4*16 + hq];
        float4 g1 = gb[d4*16 + 4 + hq];
        float4 g2 = gb[d4*16 + 8 + hq];
        float4 g3 = gb[d4*16 + 12 + hq];
        ssum += xv.x + xv.y + xv.z + xv.w;
        ssq = fmaf(xv.x,xv.x,ssq); ssq = fmaf(xv.y,xv.y,ssq);
        ssq = fmaf(xv.z,xv.z,ssq); ssq = fmaf(xv.w,xv.w,ssq);
        a0 = fmaf(xv.x,g0.x,a0); a1 = fmaf(xv.x,g0.y,a1);
        a2 = fmaf(xv.x,g0.z,a2); a3 = fmaf(xv.x,g0.w,a3);
        a0 = fmaf(xv.y,g1.x,a0); a1 = fmaf(xv.y,g1.y,a1);
        a2 = fmaf(xv.y,g1.z,a2); a3 = fmaf(xv.y,g1.w,a3);
        a0 = fmaf(xv.z,g2.x,a0); a1 = fmaf(xv.z,g2.y,a1);
        a2 = fmaf(xv.z,g2.z,a2); a3 = fmaf(xv.z,g2.w,a3);
        a0 = fmaf(xv.w,g3.x,a0); a1 = fmaf(xv.w,g3.y,a1);
        a2 = fmaf(xv.w,g3.z,a2); a3 = fmaf(xv.w,g3.w,a3);
      }
    }
    if (c+1 < NCH){
      __syncthreads();
      STOREC(c+1);
    }
  }
#undef LOADC
#undef STOREC
  int t = t0 + row;
  pacc[((size_t)(ds*BB + b)*4 + hq)*TT + t] = make_float4(a0,a1,a2,a3);
  if (hq == 0) pstat[(size_t)(ds*BB + b)*TT + t] = make_float2(ssum, ssq);
}

// ------------- K2: fused d-split reduce + online masked softmax + alpha/beta -------------
__global__ __launch_bounds__(256) void k_softmax2(
    const float4* __restrict__ pacc, const float2* __restrict__ pstat,
    const int* __restrict__ valid, const float* __restrict__ gsum,
    const float* __restrict__ cst, float* __restrict__ alpha_t,
    float* __restrict__ beta)
{
  int hq = blockIdx.x, b = blockIdx.y;
  int n = valid[b];
  int tid = threadIdx.x, lane = tid & 63, w = tid >> 6;
  float4 gq = *(const float4*)(gsum + b*NH + hq*4);
  float4 cq = *(const float4*)(cst  + b*NH + hq*4);
  float m[4], S[4], Bv[4];
#pragma unroll
  for (int j=0;j<4;j++){ m[j] = -3.0e38f; S[j]=0.f; Bv[j]=0.f; }
  for (int t = tid; t < n; t += 256){
    float4 s = make_float4(0.f,0.f,0.f,0.f);
    float ss=0.f, sq=0.f;
#pragma unroll
    for (int k=0;k<DSPLIT;k++){
      float4 v = pacc[((size_t)(k*BB+b)*4+hq)*TT + t];
      s.x+=v.x; s.y+=v.y; s.z+=v.z; s.w+=v.w;
      float2 st = pstat[(size_t)(k*BB+b)*TT + t];
      ss += st.x; sq += st.y;
    }
    float mu = ss*(1.f/DD);
    float rs = rsqrtf(sq*(1.f/DD) - mu*mu + EPS);
    float rm = rs*mu;
    float sc[4];
    sc[0] = (rs*(s.x - mu*gq.x) + cq.x)*0.125f;
    sc[1] = (rs*(s.y - mu*gq.y) + cq.y)*0.125f;
    sc[2] = (rs*(s.z - mu*gq.z) + cq.z)*0.125f;
    sc[3] = (rs*(s.w - mu*gq.w) + cq.w)*0.125f;
#pragma unroll
    for (int j=0;j<4;j++){
      float M = fmaxf(m[j], sc[j]);
      float f = expf(m[j]-M);
      float e = expf(sc[j]-M);
      S[j]  = S[j]*f + e;
      Bv[j] = Bv[j]*f + e*rm;
      m[j] = M;
    }
  }
#pragma unroll
  for (int off = 32; off >= 1; off >>= 1){
#pragma unroll
    for (int j=0;j<4;j++){
      float om = __shfl_xor(m[j], off, 64);
      float oS = __shfl_xor(S[j], off, 64);
      float oB = __shfl_xor(Bv[j], off, 64);
      float M = fmaxf(m[j], om);
      float f1 = expf(m[j]-M), f2 = expf(om-M);
      S[j]  = S[j]*f1 + oS*f2;
      Bv[j] = Bv[j]*f1 + oB*f2;
      m[j] = M;
    }
  }
  __shared__ float sm[4][12];
  if (lane == 0){
#pragma unroll
    for (int j=0;j<4;j++){ sm[w][j]=m[j]; sm[w][4+j]=S[j]; sm[w][8+j]=Bv[j]; }
  }
  __syncthreads();
#pragma unroll
  for (int j=0;j<4;j++){ m[j]=sm[0][j]; S[j]=sm[0][4+j]; Bv[j]=sm[0][8+j]; }
#pragma unroll
  for (int w2=1; w2<4; w2++){
#pragma unroll
    for (int j=0;j<4;j++){
      float om = sm[w2][j], oS = sm[w2][4+j], oB = sm[w2][8+j];
      float M = fmaxf(m[j], om);
      float f1 = expf(m[j]-M), f2 = expf(om-M);
      S[j]  = S[j]*f1 + oS*f2;
      Bv[j] = Bv[j]*f1 + oB*f2;
      m[j] = M;
    }
  }
  float inv[4];
#pragma unroll
  for (int j=0;j<4;j++) inv[j] = 1.f/S[j];
  if (tid == 0){
#pragma unroll
    for (int j=0;j<4;j++) beta[b*NH + hq*4 + j] = Bv[j]*inv[j];
  }
  for (int t = tid; t < n; t += 256){
    float4 s = make_float4(0.f,0.f,0.f,0.f);
    float ss=0.f, sq=0.f;
#pragma unroll
    for (int k=0;k<DSPLIT;k++){
      float4 v = pacc[((size_t)(k*BB+b)*4+hq)*TT + t];
      s.x+=v.x; s.y+=v.y; s.z+=v.z; s.w+=v.w;
      float2 st = pstat[(size_t)(k*BB+b)*TT + t];
      ss += st.x; sq += st.y;
    }
    float mu = ss*(1.f/DD);
    float rs = rsqrtf(sq*(1.f/DD) - mu*mu + EPS);
    float4 av;
    av.x = expf((rs*(s.x - mu*gq.x) + cq.x)*0.125f - m[0]) * rs * inv[0];
    av.y = expf((rs*(s.y - mu*gq.y) + cq.y)*0.125f - m[1]) * rs * inv[1];
    av.z = expf((rs*(s.z - mu*gq.z) + cq.z)*0.125f - m[2]) * rs * inv[2];
    av.w = expf((rs*(s.w - mu*gq.w) + cq.w)*0.125f - m[3]) * rs * inv[3];
    *(float4*)(alpha_t + ((size_t)b*TT + t)*NH + hq*4) = av;
  }
}

// ------------- K3: partial u accumulation, 4-deep prefetch -------------
// 512 threads, thread owns 2 d. Blocks with t0 >= valid exit WITHOUT writing;
// k_uctx sums only ceil(valid/ct) chunks.
#define BODYA(XC, TL) { \
  float4 q0=av[(TL)*4+0], q1=av[(TL)*4+1], q2=av[(TL)*4+2], q3=av[(TL)*4+3]; \
  float aa[16]={q0.x,q0.y,q0.z,q0.w,q1.x,q1.y,q1.z,q1.w, \
                q2.x,q2.y,q2.z,q2.w,q3.x,q3.y,q3.z,q3.w}; \
  _Pragma("unroll") \
  for (int h=0;h<16;h++){ ax[h]=fmaf(aa[h],(XC).x,ax[h]); ay[h]=fmaf(aa[h],(XC).y,ay[h]); } }

__global__ __launch_bounds__(512, 4) void k_accum(
    const float* __restrict__ X, const float* __restrict__ alpha_t,
    const int* __restrict__ valid, float* __restrict__ part, int ct)
{
  int c = blockIdx.x, b = blockIdx.y;
  int tid = threadIdx.x;
  int t0 = c*ct;
  int vb = valid[b];
  if (t0 >= vb) return;
  int tend = min(vb, t0 + ct);
  float ax[16], ay[16];
#pragma unroll
  for (int h=0;h<16;h++){ ax[h]=0.f; ay[h]=0.f; }
  __shared__ float4 at[2][256];
  const float2* xb = (const float2*)(X + (size_t)b*TT*DD);
  const float4* ab = (const float4*)(alpha_t + (size_t)b*TT*NH);
  int nsub = (tend - t0 + 63) >> 6;
  float4 nxt = make_float4(0.f,0.f,0.f,0.f);
  if (tid < 256) at[0][tid] = ab[(size_t)t0*4 + tid];
  for (int s=0; s<nsub; s++){
    if (s+1 < nsub && tid < 256) nxt = ab[(size_t)(t0+(s+1)*64)*4 + tid];
    __syncthreads();
    int ts = t0 + s*64;
    int te = min(tend - ts, 64);
    const float4* av = at[s&1];
    if (te == 64){
      size_t rb = (size_t)ts*(DD/2) + tid;
      float2 x0 = xb[rb], x1 = xb[rb+512], x2 = xb[rb+1024], x3 = xb[rb+1536];
      for (int tl=0; tl<64; tl+=4){
        float2 c0=x0, c1=x1, c2=x2, c3=x3;
        if (tl < 60){
          size_t nb = rb + (size_t)(tl+4)*512;
          x0 = xb[nb]; x1 = xb[nb+512]; x2 = xb[nb+1024]; x3 = xb[nb+1536];
        }
        BODYA(c0, tl+0);
        BODYA(c1, tl+1);
        BODYA(c2, tl+2);
        BODYA(c3, tl+3);
      }
    } else {
      for (int tl=0; tl<te; tl++){
        float2 xc = xb[(size_t)(ts+tl)*(DD/2) + tid];
        BODYA(xc, tl);
      }
    }
    if (s+1 < nsub){
      __syncthreads();
      if (tid < 256) at[(s+1)&1][tid] = nxt;
    }
  }
  float* pp = part + (((size_t)c*BB + b)*NH)*DD;
#pragma unroll
  for (int h=0;h<16;h++)
    *(float2*)(pp + (size_t)h*DD + tid*2) = make_float2(ax[h], ay[h]);
}

// ------------- K4: fused u-finalize (valid chunks only) + ctx = Wv_h @ u + bv -------------
__global__ __launch_bounds__(256) void k_uctx(const float* __restrict__ part,
   const int* __restrict__ valid, const float* __restrict__ beta,
   const float* __restrict__ g_kv, const float* __restrict__ b_kv,
   const float* __restrict__ Wfull, const float* __restrict__ bfull,
   float* __restrict__ ctx, int ct, int nc)
{
  int h = blockIdx.x, b = blockIdx.y;
  int tid = threadIdx.x;
  __shared__ float ul[DD];
  __shared__ float Wl[64][65];
  __shared__ float red2[4][64];
  {
    int nv = (valid[b] + ct - 1) / ct;
    if (nv > nc) nv = nc;
    int d = tid*4;
    float4 s = make_float4(0.f,0.f,0.f,0.f);
    for (int c=0;c<nv;c++){
      float4 v = *(const float4*)(part + (((size_t)c*BB + b)*NH + h)*DD + d);
      s.x+=v.x; s.y+=v.y; s.z+=v.z; s.w+=v.w;
    }
    float be = beta[b*NH+h];
    float4 g = *(const float4*)(g_kv + d);
    float4 bv = *(const float4*)(b_kv + d);
    float4 r;
    r.x = fmaf(g.x, s.x-be, bv.x);
    r.y = fmaf(g.y, s.y-be, bv.y);
    r.z = fmaf(g.z, s.z-be, bv.z);
    r.w = fmaf(g.w, s.w-be, bv.w);
    ((float4*)ul)[tid] = r;
  }
  __syncthreads();
  int j = tid & 63, quart = tid >> 6;
  float acc = 0.f;
  const float* Wv = Wfull + (size_t)2*DD*DD;
  for (int dc=0; dc<DD; dc+=64){
#pragma unroll
    for (int p=0;p<4;p++){
      int fi = p*256 + tid, r = fi >> 4, q4 = fi & 15;
      float4 v = *(const float4*)(Wv + (size_t)(h*HDIM + r)*DD + dc + q4*4);
      Wl[r][q4*4+0]=v.x; Wl[r][q4*4+1]=v.y; Wl[r][q4*4+2]=v.z; Wl[r][q4*4+3]=v.w;
    }
    __syncthreads();
#pragma unroll
    for (int i=0;i<16;i++)
      acc = fmaf(Wl[j][quart*16+i], ul[dc + quart*16 + i], acc);
    __syncthreads();
  }
  red2[quart][j] = acc;
  __syncthreads();
  if (quart == 0){
    float v = red2[0][j] + red2[1][j] + red2[2][j] + red2[3][j];
    ctx[(size_t)b*DD + h*HDIM + j] = v + bfull[2*DD + h*HDIM + j];
  }
}

// ------------- K5: fused out-proj reduce + out = LN(o + h_t) -------------
__global__ __launch_bounds__(256) void k_outln(const float* __restrict__ p2,
   const float* __restrict__ obias, const float* __restrict__ h_t,
   const float* __restrict__ g, const float* __restrict__ bb,
   float* __restrict__ out)
{
  int b = blockIdx.x, tid = threadIdx.x;
  __shared__ float red[64];
  int e = tid*4;
  float4 a = *(const float4*)(obias + e);
#pragma unroll
  for (int k=0;k<8;k++){
    float4 v = *(const float4*)(p2 + ((size_t)k*BB + b)*DD + e);
    a.x+=v.x; a.y+=v.y; a.z+=v.z; a.w+=v.w;
  }
  float4 r = ((const float4*)(h_t + (size_t)b*DD))[tid];
  a.x+=r.x; a.y+=r.y; a.z+=r.z; a.w+=r.w;
  float s = a.x + a.y + a.z + a.w;
  s = bredSum(s, red);
  float mu = s * (1.f/DD);
  float d0=a.x-mu, d1=a.y-mu, d2=a.z-mu, d3=a.w-mu;
  float s2 = d0*d0 + d1*d1 + d2*d2 + d3*d3;
  s2 = bredSum(s2, red);
  float rs = rsqrtf(s2*(1.f/DD) + EPS);
  float4 gv = ((const float4*)g)[tid], bv = ((const float4*)bb)[tid];
  float4 ov;
  ov.x = fmaf(d0*rs, gv.x, bv.x);
  ov.y = fmaf(d1*rs, gv.y, bv.y);
  ov.z = fmaf(d2*rs, gv.z, bv.z);
  ov.w = fmaf(d3*rs, gv.w, bv.w);
  ((float4*)(out + (size_t)b*DD))[tid] = ov;
}

extern "C" void kernel_launch(void* const* d_in, const int* in_sizes, int n_in,
                              void* d_out, int out_size, void* d_ws, size_t ws_size,
                              hipStream_t stream) {
  const float* h_t     = (const float*)d_in[0];
  const float* H_p     = (const float*)d_in[1];
  const int*   valid   = (const int*)  d_in[2];
  const float* ln_q_g  = (const float*)d_in[3];
  const float* ln_q_b  = (const float*)d_in[4];
  const float* ln_kv_g = (const float*)d_in[5];
  const float* ln_kv_b = (const float*)d_in[6];
  const float* ln_out_g= (const float*)d_in[7];
  const float* ln_out_b= (const float*)d_in[8];
  const float* log_tau = (const float*)d_in[9];
  const float* in_w    = (const float*)d_in[10];
  const float* in_b    = (const float*)d_in[11];
  const float* out_w   = (const float*)d_in[12];
  const float* out_b   = (const float*)d_in[13];
  float* out = (float*)d_out;

  float* ws     = (float*)d_ws;
  float* q      = ws;
  float* gs_t   = q      + BB*DD;
  float* gsum   = gs_t   + (size_t)BB*DD*NH;
  float* cst    = gsum   + BB*NH;
  float* alpha  = cst    + BB*NH;
  float* beta   = alpha  + (size_t)BB*TT*NH;
  float* ctx    = beta   + BB*NH;
  float* part   = ctx    + BB*DD;
  // "part" region is time-shared: in-proj gemm partials (consumed by k_prep_s),
  // then pacc/pstat (consumed by k_softmax2), then accum partials (k_accum ->
  // k_uctx), then out-proj gemm partials (consumed by k_outln).
  const size_t pacc_floats = (size_t)DSPLIT*BB*NH*TT;      // 2,097,152
  float4* pacc  = (float4*)part;
  float2* pstat = (float2*)(part + pacc_floats);
  const size_t pacc_region = pacc_floats + (size_t)DSPLIT*BB*TT*2;

  size_t base_floats = (size_t)(part - ws);
  int nc = 16;
  size_t accum_region = (size_t)nc*BB*NH*DD;
  size_t region = accum_region > pacc_region ? accum_region : pacc_region;
  if ((base_floats + region) * sizeof(float) > ws_size){
    nc = 8;
  }
  int ct = TT / nc;

  k_qln<<<BB, 256, 0, stream>>>(h_t, ln_q_g, ln_q_b, log_tau, q);
  k_gemmsplit<<<dim3(16,8), 256, 0, stream>>>(q, in_w, part);
  k_prep_s<<<dim3(NH,BB), 256, 0, stream>>>(part, in_w, in_b, ln_kv_g, ln_kv_b, gs_t, gsum, cst);
  k_scores<<<dim3((TT/SR)*DSPLIT,BB), 256, 0, stream>>>(H_p, valid, gs_t, pacc, pstat);
  k_softmax2<<<dim3(4,BB), 256, 0, stream>>>(pacc, pstat, valid, gsum, cst, alpha, beta);
  k_accum<<<dim3(nc,BB), 512, 0, stream>>>(H_p, alpha, valid, part, ct);
  k_uctx<<<dim3(NH,BB), 256, 0, stream>>>(part, valid, beta, ln_kv_g, ln_kv_b, in_w, in_b, ctx, ct, nc);
  k_gemmsplit<<<dim3(16,8), 256, 0, stream>>>(ctx, out_w, part);
  k_outln<<<BB, 256, 0, stream>>>(part, out_b, h_t, ln_out_g, ln_out_b, out);
}